// Round 1
// baseline (692.653 us; speedup 1.0000x reference)
//
#include <hip/hip_runtime.h>
#include <stdint.h>

#define DEVI __device__ __forceinline__

typedef __attribute__((ext_vector_type(8))) short s16x8;   // 8 bf16 in 4 VGPRs
typedef __attribute__((ext_vector_type(4))) float f32x4;   // MFMA accumulator

// ---------------------------------------------------------------- helpers

DEVI unsigned short f2bf(float f) {
  // round-to-nearest-even f32 -> bf16 (inputs finite; no NaN handling needed)
  uint32_t u = __float_as_uint(f);
  uint32_t r = (u + 0x7fffu + ((u >> 16) & 1u)) >> 16;
  return (unsigned short)r;
}

DEVI void load_lds16(const void* g, void* lds) {
  // async global->LDS, 16B per lane; LDS dest is wave-uniform base + lane*16
  __builtin_amdgcn_global_load_lds(
      (const __attribute__((address_space(1))) void*)g,
      (__attribute__((address_space(3))) void*)lds, 16, 0, 0);
}

// 128x128 output tile, K=256 (4 steps of BK=64), A@B^T, both row-major ld=256.
// 4 waves in 2x2; each wave owns a 64x64 sub-tile as 4x4 fragments of 16x16.
DEVI void gemm_tile(const unsigned short* __restrict__ At,
                    const unsigned short* __restrict__ Bt,
                    unsigned short* ldsA, unsigned short* ldsB,
                    f32x4 (&acc)[4][4])
{
  const int tid  = threadIdx.x;
  const int wid  = tid >> 6;
  const int lane = tid & 63;
  const int wr = wid >> 1, wc = wid & 1;

  const f32x4 zero = {0.f, 0.f, 0.f, 0.f};
#pragma unroll
  for (int i = 0; i < 4; ++i)
#pragma unroll
    for (int j = 0; j < 4; ++j)
      acc[i][j] = zero;

#pragma unroll 1
  for (int ks = 0; ks < 4; ++ks) {
    const int k0 = ks * 64;
    // stage A and B tiles [128][64] bf16 (16KB each) via global_load_lds.
    // chunk c = 1KB = 8 rows; lane l covers row c*8 + l/8, k-elems (l%8)*8..+8
#pragma unroll
    for (int c = wid; c < 16; c += 4) {
      const int row  = c * 8 + (lane >> 3);
      const int kofs = (lane & 7) * 8;
      load_lds16(At + (size_t)row * 256 + k0 + kofs, (char*)ldsA + c * 1024);
      load_lds16(Bt + (size_t)row * 256 + k0 + kofs, (char*)ldsB + c * 1024);
    }
    __syncthreads();
#pragma unroll
    for (int kk = 0; kk < 2; ++kk) {
      s16x8 av[4], bv[4];
#pragma unroll
      for (int i = 0; i < 4; ++i) {
        av[i] = *(const s16x8*)&ldsA[(wr * 64 + i * 16 + (lane & 15)) * 64 + kk * 32 + (lane >> 4) * 8];
        bv[i] = *(const s16x8*)&ldsB[(wc * 64 + i * 16 + (lane & 15)) * 64 + kk * 32 + (lane >> 4) * 8];
      }
#pragma unroll
      for (int i = 0; i < 4; ++i)
#pragma unroll
        for (int j = 0; j < 4; ++j)
          acc[i][j] = __builtin_amdgcn_mfma_f32_16x16x32_bf16(av[i], bv[j], acc[i][j], 0, 0, 0);
    }
    __syncthreads();
  }
}

// ---------------------------------------------------------------- kernels

__global__ __launch_bounds__(256) void k_convert(const float* __restrict__ src,
                                                 unsigned short* __restrict__ dst, int n4) {
  int i = blockIdx.x * blockDim.x + threadIdx.x;
  const int stride = gridDim.x * blockDim.x;
  for (; i < n4; i += stride) {
    const float4 v = ((const float4*)src)[i];
    ushort4 o;
    o.x = f2bf(v.x); o.y = f2bf(v.y); o.z = f2bf(v.z); o.w = f2bf(v.w);
    ((ushort4*)dst)[i] = o;
  }
}

// mdesc = (desc @ Wf^T + bf) / 4, output bf16. grid: (128 mtiles, 2 etiles, 2 which)
__global__ __launch_bounds__(256) void k_proj(
    const unsigned short* __restrict__ d0bf, const unsigned short* __restrict__ d1bf,
    const unsigned short* __restrict__ wfbf, const float* __restrict__ bfv,
    unsigned short* __restrict__ md0, unsigned short* __restrict__ md1)
{
  __shared__ __align__(16) unsigned short ldsA[128 * 64];
  __shared__ __align__(16) unsigned short ldsB[128 * 64];
  const unsigned short* src = blockIdx.z ? d1bf : d0bf;
  unsigned short*       dst = blockIdx.z ? md1  : md0;
  const int bm0 = blockIdx.x * 128;
  const int be0 = blockIdx.y * 128;
  f32x4 acc[4][4];
  gemm_tile(src + (size_t)bm0 * 256, wfbf + (size_t)be0 * 256, ldsA, ldsB, acc);

  const int lane = threadIdx.x & 63, wid = threadIdx.x >> 6;
  const int wr = wid >> 1, wc = wid & 1;
#pragma unroll
  for (int i = 0; i < 4; ++i) {
#pragma unroll
    for (int j = 0; j < 4; ++j) {
      const int ge = be0 + wc * 64 + j * 16 + (lane & 15);
      const float bias = bfv[ge];
#pragma unroll
      for (int r = 0; r < 4; ++r) {
        const int gm = bm0 + wr * 64 + i * 16 + (lane >> 4) * 4 + r;
        dst[(size_t)gm * 256 + ge] = f2bf((acc[i][j][r] + bias) * 0.25f);
      }
    }
  }
}

// logvar = desc @ Wl^T + bl (f32). One wave per row.
__global__ __launch_bounds__(256) void k_logvar(
    const float* __restrict__ desc, const float* __restrict__ Wl,
    const float* __restrict__ bl, float* __restrict__ olv)
{
  const int wid = threadIdx.x >> 6, lane = threadIdx.x & 63;
  const int row = blockIdx.x * 4 + wid;  // 0..16383
  const float4 v  = *(const float4*)(desc + (size_t)row * 256 + lane * 4);
  const float4 w0 = *(const float4*)(Wl + lane * 4);
  const float4 w1 = *(const float4*)(Wl + 256 + lane * 4);
  float s0 = v.x * w0.x + v.y * w0.y + v.z * w0.z + v.w * w0.w;
  float s1 = v.x * w1.x + v.y * w1.y + v.z * w1.z + v.w * w1.w;
#pragma unroll
  for (int off = 32; off > 0; off >>= 1) {
    s0 += __shfl_down(s0, off);
    s1 += __shfl_down(s1, off);
  }
  if (lane == 0) {
    olv[(size_t)row * 2 + 0] = s0 + bl[0];
    olv[(size_t)row * 2 + 1] = s1 + bl[1];
  }
}

// Pass 1: recompute sim tile, produce per-tile row/col (max, sumexp) partials.
// grid: (bn=32, bm=32, b=4)
__global__ __launch_bounds__(256) void k_stats(
    const unsigned short* __restrict__ md0, const unsigned short* __restrict__ md1,
    float* __restrict__ rpmax, float* __restrict__ rpsum,
    float* __restrict__ cpmax, float* __restrict__ cpsum)
{
  __shared__ __align__(16) char smem[37120];
  unsigned short* ldsA = (unsigned short*)smem;            // 16KB (GEMM phase)
  unsigned short* ldsB = (unsigned short*)(smem + 16384);  // 16KB (GEMM phase)
  float (*simbuf)[129] = (float (*)[129])smem;             // 33024B (epilogue, aliases staging)
  float (*pm)[4]  = (float (*)[4])(smem + 33024);
  float (*psm)[4] = (float (*)[4])(smem + 34048);
  float (*cpm)[2] = (float (*)[2])(smem + 35072);
  float (*cps)[2] = (float (*)[2])(smem + 36096);

  const int b = blockIdx.z, bn = blockIdx.x, bm = blockIdx.y;
  const int bm0 = bm * 128, bn0 = bn * 128;
  f32x4 acc[4][4];
  gemm_tile(md0 + ((size_t)b * 4096 + bm0) * 256,
            md1 + ((size_t)b * 4096 + bn0) * 256, ldsA, ldsB, acc);

  const int tid = threadIdx.x, lane = tid & 63, wid = tid >> 6;
  const int wr = wid >> 1, wc = wid & 1;
  float ccm = -3.0e38f, ccs = 0.f;  // running col (max,sum) for tid<128

#pragma unroll 1
  for (int h = 0; h < 2; ++h) {
    __syncthreads();
    if (wr == h) {
#pragma unroll
      for (int i = 0; i < 4; ++i)
#pragma unroll
        for (int j = 0; j < 4; ++j)
#pragma unroll
          for (int r = 0; r < 4; ++r)
            simbuf[i * 16 + (lane >> 4) * 4 + r][wc * 64 + j * 16 + (lane & 15)] = acc[i][j][r];
    }
    __syncthreads();
    {  // row partials: thread -> (row=tid&63, quarter q), 32 cols each
      const int row = tid & 63, q = tid >> 6;
      float mx = -3.0e38f;
      for (int c = 0; c < 32; ++c) mx = fmaxf(mx, simbuf[row][q * 32 + c]);
      float s = 0.f;
      for (int c = 0; c < 32; ++c) s += __expf(simbuf[row][q * 32 + c] - mx);
      pm[row][q] = mx; psm[row][q] = s;
    }
    {  // col partials: thread -> (col=tid&127, half rh), 32 rows each
      const int col = tid & 127, rh = tid >> 7;
      float mx = -3.0e38f;
      for (int r = 0; r < 32; ++r) mx = fmaxf(mx, simbuf[rh * 32 + r][col]);
      float s = 0.f;
      for (int r = 0; r < 32; ++r) s += __expf(simbuf[rh * 32 + r][col] - mx);
      cpm[col][rh] = mx; cps[col][rh] = s;
    }
    __syncthreads();
    if (tid < 64) {  // merge 4 row quarters, write tile row-partial
      float M = pm[tid][0];
#pragma unroll
      for (int q = 1; q < 4; ++q) M = fmaxf(M, pm[tid][q]);
      float S = 0.f;
#pragma unroll
      for (int q = 0; q < 4; ++q) S += psm[tid][q] * __expf(pm[tid][q] - M);
      const int gm = bm0 + h * 64 + tid;
      rpmax[((size_t)b * 32 + bn) * 4096 + gm] = M;
      rpsum[((size_t)b * 32 + bn) * 4096 + gm] = S;
    }
    if (tid < 128) {  // merge 2 col halves into running (max,sum)
      float M = fmaxf(cpm[tid][0], cpm[tid][1]);
      float S = cps[tid][0] * __expf(cpm[tid][0] - M) + cps[tid][1] * __expf(cpm[tid][1] - M);
      const float nm = fmaxf(ccm, M);
      ccs = ccs * __expf(ccm - nm) + S * __expf(M - nm);
      ccm = nm;
    }
  }
  if (tid < 128) {
    const int gn = bn0 + tid;
    cpmax[((size_t)b * 32 + bm) * 4096 + gn] = ccm;
    cpsum[((size_t)b * 32 + bm) * 4096 + gn] = ccs;
  }
}

// merge 32 tile-partials -> final (max, 1/sum). grid 64 x 256 threads = 16384 rows/cols
__global__ __launch_bounds__(256) void k_reduce(
    const float* __restrict__ pmax, const float* __restrict__ psum,
    float* __restrict__ omax, float* __restrict__ oinv)
{
  const int i = blockIdx.x * 256 + threadIdx.x;  // b*4096 + idx
  const int b = i >> 12, m = i & 4095;
  const float* PM = pmax + (size_t)b * 32 * 4096 + m;
  const float* PS = psum + (size_t)b * 32 * 4096 + m;
  float M = -3.0e38f;
#pragma unroll
  for (int t = 0; t < 32; ++t) M = fmaxf(M, PM[(size_t)t * 4096]);
  float S = 0.f;
#pragma unroll
  for (int t = 0; t < 32; ++t) S += PS[(size_t)t * 4096] * __expf(PM[(size_t)t * 4096] - M);
  omax[i] = M;
  oinv[i] = 1.0f / S;
}

// Pass 2: recompute sim tile, write both normalized outputs (coalesced via LDS).
__global__ __launch_bounds__(256) void k_out(
    const unsigned short* __restrict__ md0, const unsigned short* __restrict__ md1,
    const float* __restrict__ rowmax, const float* __restrict__ rowinv,
    const float* __restrict__ colmax, const float* __restrict__ colinv,
    float* __restrict__ p01, float* __restrict__ p10)
{
  __shared__ __align__(16) char smem[33024];
  unsigned short* ldsA = (unsigned short*)smem;
  unsigned short* ldsB = (unsigned short*)(smem + 16384);
  float (*simbuf)[129] = (float (*)[129])smem;

  const int b = blockIdx.z, bn = blockIdx.x, bm = blockIdx.y;
  const int bm0 = bm * 128, bn0 = bn * 128;
  f32x4 acc[4][4];
  gemm_tile(md0 + ((size_t)b * 4096 + bm0) * 256,
            md1 + ((size_t)b * 4096 + bn0) * 256, ldsA, ldsB, acc);

  const int tid = threadIdx.x, lane = tid & 63, wid = tid >> 6;
  const int wr = wid >> 1, wc = wid & 1;
  const float* RM = rowmax + (size_t)b * 4096;
  const float* RI = rowinv + (size_t)b * 4096;
  const float* CM = colmax + (size_t)b * 4096;
  const float* CI = colinv + (size_t)b * 4096;
  float* o01 = p01 + (size_t)b * 4096 * 4096;
  float* o10 = p10 + (size_t)b * 4096 * 4096;

#pragma unroll 1
  for (int h = 0; h < 2; ++h) {
    __syncthreads();
    if (wr == h) {
#pragma unroll
      for (int i = 0; i < 4; ++i)
#pragma unroll
        for (int j = 0; j < 4; ++j)
#pragma unroll
          for (int r = 0; r < 4; ++r)
            simbuf[i * 16 + (lane >> 4) * 4 + r][wc * 64 + j * 16 + (lane & 15)] = acc[i][j][r];
    }
    __syncthreads();
    // each wave writes 16 rows; lane covers col `ch*64+lane` -> 256B/instr stores
#pragma unroll 1
    for (int rr = 0; rr < 16; ++rr) {
      const int rloc = wid * 16 + rr;
      const int gm = bm0 + h * 64 + rloc;
      const float rm = RM[gm], ri = RI[gm];
#pragma unroll
      for (int ch = 0; ch < 2; ++ch) {
        const int cloc = ch * 64 + lane;
        const int gn = bn0 + cloc;
        const float v = simbuf[rloc][cloc];
        const size_t oi = (size_t)gm * 4096 + gn;
        o01[oi] = __expf(v - rm) * ri;
        o10[oi] = __expf(v - CM[gn]) * CI[gn];
      }
    }
  }
}

// ---------------------------------------------------------------- launch

extern "C" void kernel_launch(void* const* d_in, const int* in_sizes, int n_in,
                              void* d_out, int out_size, void* d_ws, size_t ws_size,
                              hipStream_t stream)
{
  const float* desc0 = (const float*)d_in[0];
  const float* desc1 = (const float*)d_in[1];
  const float* Wf    = (const float*)d_in[2];
  const float* bf    = (const float*)d_in[3];
  const float* Wl    = (const float*)d_in[4];
  const float* bl    = (const float*)d_in[5];

  float* out  = (float*)d_out;
  float* p01  = out;                                   // [4,4096,4096]
  float* p10  = out + (size_t)4 * 4096 * 4096;         // [4,4096,4096]
  float* lv01 = out + (size_t)8 * 4096 * 4096;         // [4,4096,2]
  float* lv10 = lv01 + (size_t)4 * 4096 * 2;           // [4,4096,2]

  char* ws = (char*)d_ws;
  // layout (bytes): d0bf 8M | d1bf 8M | wfbf 128K | md0 8M | md1 8M  (~32.1MB)
  unsigned short* d0bf = (unsigned short*)(ws);
  unsigned short* d1bf = (unsigned short*)(ws + 8388608);
  unsigned short* wfbf = (unsigned short*)(ws + 16777216);
  unsigned short* md0  = (unsigned short*)(ws + 16908288);
  unsigned short* md1  = (unsigned short*)(ws + 25296896);
  // d0bf region reused after k_proj for partials; d1bf region for finals
  float* rpmax  = (float*)d0bf;
  float* rpsum  = rpmax + 524288;
  float* cpmaxp = rpmax + 2 * 524288;
  float* cpsump = rpmax + 3 * 524288;
  float* rowmax = (float*)d1bf;
  float* rowinv = rowmax + 16384;
  float* colmax = rowmax + 32768;
  float* colinv = rowmax + 49152;

  k_convert<<<dim3(1024), dim3(256), 0, stream>>>(desc0, d0bf, 4194304 / 4);
  k_convert<<<dim3(1024), dim3(256), 0, stream>>>(desc1, d1bf, 4194304 / 4);
  k_convert<<<dim3(64),   dim3(256), 0, stream>>>(Wf, wfbf, 65536 / 4);
  k_proj<<<dim3(128, 2, 2), dim3(256), 0, stream>>>(d0bf, d1bf, wfbf, bf, md0, md1);
  k_logvar<<<dim3(4096), dim3(256), 0, stream>>>(desc0, Wl, bl, lv01);
  k_logvar<<<dim3(4096), dim3(256), 0, stream>>>(desc1, Wl, bl, lv10);
  k_stats<<<dim3(32, 32, 4), dim3(256), 0, stream>>>(md0, md1, rpmax, rpsum, cpmaxp, cpsump);
  k_reduce<<<dim3(64), dim3(256), 0, stream>>>(rpmax, rpsum, rowmax, rowinv);
  k_reduce<<<dim3(64), dim3(256), 0, stream>>>(cpmaxp, cpsump, colmax, colinv);
  k_out<<<dim3(32, 32, 4), dim3(256), 0, stream>>>(md0, md1, rowmax, rowinv, colmax, colinv, p01, p10);
}